// Round 3
// baseline (3842.991 us; speedup 1.0000x reference)
//
#include <hip/hip_runtime.h>

// GraphConvLayer on MI355X.
// N=100000 nodes, E=6400000 edges, D=10.
// ws footprint: only N floats (counts, 400KB). seg_sum accumulates into d_out.

__global__ __launch_bounds__(256) void zero_kernel(float4* __restrict__ out4, int n_out4,
                                                   float4* __restrict__ cnt4, int n_cnt4) {
    int i = blockIdx.x * blockDim.x + threadIdx.x;
    float4 z = make_float4(0.f, 0.f, 0.f, 0.f);
    if (i < n_out4) out4[i] = z;
    if (i < n_cnt4) cnt4[i] = z;
}

// Edge phase: msgs = relu(concat(ef, nf[nb]) @ W1p + b1p) @ W2p; atomic-scatter into seg_sum(=d_out), counts.
// 2 edges per thread; weights staged in LDS with rows padded to 12 floats (48B, 16B-aligned -> ds_read_b128).
__global__ __launch_bounds__(256) void edge_kernel(
    const float* __restrict__ node_feats,    // [N,10]
    const int*   __restrict__ edges,         // [2,E]
    const float* __restrict__ edge_features, // [E,10]
    const float* __restrict__ W1p,           // [20,10]
    const float* __restrict__ b1p,           // [10]
    const float* __restrict__ W2p,           // [10,10]
    float* __restrict__ seg_sum,             // [N,10]  (== d_out)
    float* __restrict__ counts,              // [N]     (== d_ws)
    int E)
{
    __shared__ float lw1[20][12];
    __shared__ float lw2[10][12];
    __shared__ float lb1[12];

    const int t = threadIdx.x;
    for (int i = t; i < 310; i += 256) {
        if (i < 200)      lw1[i / 10][i % 10] = W1p[i];
        else if (i < 300) { int j = i - 200; lw2[j / 10][j % 10] = W2p[j]; }
        else              lb1[i - 300] = b1p[i - 300];
    }
    __syncthreads();

    const int e0 = blockIdx.x * 512 + t;
    const int e1 = e0 + 256;
    const bool vA = e0 < E;
    const bool vB = e1 < E;

    int nbA = 0, ndA = 0, nbB = 0, ndB = 0;
    if (vA) { nbA = edges[e0]; ndA = edges[E + e0]; }
    if (vB) { nbB = edges[e1]; ndB = edges[E + e1]; }

    float hA[20], hB[20];
#pragma unroll
    for (int i = 0; i < 20; ++i) { hA[i] = 0.f; hB[i] = 0.f; }

    if (vA) {
        const float2* ef2 = reinterpret_cast<const float2*>(edge_features) + (size_t)e0 * 5;
        const float2* nf2 = reinterpret_cast<const float2*>(node_feats) + (size_t)nbA * 5;
#pragma unroll
        for (int k = 0; k < 5; ++k) {
            float2 a = ef2[k]; hA[2 * k] = a.x; hA[2 * k + 1] = a.y;
            float2 b = nf2[k]; hA[10 + 2 * k] = b.x; hA[10 + 2 * k + 1] = b.y;
        }
    }
    if (vB) {
        const float2* ef2 = reinterpret_cast<const float2*>(edge_features) + (size_t)e1 * 5;
        const float2* nf2 = reinterpret_cast<const float2*>(node_feats) + (size_t)nbB * 5;
#pragma unroll
        for (int k = 0; k < 5; ++k) {
            float2 a = ef2[k]; hB[2 * k] = a.x; hB[2 * k + 1] = a.y;
            float2 b = nf2[k]; hB[10 + 2 * k] = b.x; hB[10 + 2 * k + 1] = b.y;
        }
    }

    float sA[10], sB[10];
#pragma unroll
    for (int j = 0; j < 10; ++j) { sA[j] = lb1[j]; sB[j] = lb1[j]; }
#pragma unroll
    for (int i = 0; i < 20; ++i) {
        float a = hA[i], b = hB[i];
#pragma unroll
        for (int j = 0; j < 10; ++j) {
            float w = lw1[i][j];
            sA[j] = fmaf(a, w, sA[j]);
            sB[j] = fmaf(b, w, sB[j]);
        }
    }
#pragma unroll
    for (int j = 0; j < 10; ++j) { sA[j] = fmaxf(sA[j], 0.f); sB[j] = fmaxf(sB[j], 0.f); }

    float mA[10], mB[10];
#pragma unroll
    for (int k = 0; k < 10; ++k) { mA[k] = 0.f; mB[k] = 0.f; }
#pragma unroll
    for (int i = 0; i < 10; ++i) {
        float a = sA[i], b = sB[i];
#pragma unroll
        for (int j = 0; j < 10; ++j) {
            float w = lw2[i][j];
            mA[j] = fmaf(a, w, mA[j]);
            mB[j] = fmaf(b, w, mB[j]);
        }
    }

    if (vA) {
        float* dst = seg_sum + (size_t)ndA * 10;
#pragma unroll
        for (int k = 0; k < 10; ++k) unsafeAtomicAdd(dst + k, mA[k]);
        unsafeAtomicAdd(counts + ndA, 1.0f);
    }
    if (vB) {
        float* dst = seg_sum + (size_t)ndB * 10;
#pragma unroll
        for (int k = 0; k < 10; ++k) unsafeAtomicAdd(dst + k, mB[k]);
        unsafeAtomicAdd(counts + ndB, 1.0f);
    }
}

// Node phase: in-place on d_out. Each thread owns one row: reads seg_sum row n + counts[n],
// computes relu(concat(nf, agg) @ W1u + b1u) @ W2u, overwrites row n.
__global__ __launch_bounds__(256) void node_kernel(
    const float* __restrict__ node_feats, // [N,10]
    const float* __restrict__ counts,     // [N]
    const float* __restrict__ W1u,        // [20,20]
    const float* __restrict__ b1u,        // [20]
    const float* __restrict__ W2u,        // [20,10]
    float* __restrict__ inout,            // [N,10]  seg_sum in, result out
    int N)
{
    __shared__ float lw1[20][20];
    __shared__ float lw2[20][12];
    __shared__ float lb1[20];

    const int t = threadIdx.x;
    for (int i = t; i < 620; i += 256) {
        if (i < 400)      lw1[i / 20][i % 20] = W1u[i];
        else if (i < 420) lb1[i - 400] = b1u[i - 400];
        else              { int j = i - 420; lw2[j / 10][j % 10] = W2u[j]; }
    }
    __syncthreads();

    const int n = blockIdx.x * 256 + t;
    if (n >= N) return;

    float u[20];
    const float2* nf2 = reinterpret_cast<const float2*>(node_feats) + (size_t)n * 5;
#pragma unroll
    for (int k = 0; k < 5; ++k) {
        float2 v = nf2[k];
        u[2 * k] = v.x; u[2 * k + 1] = v.y;
    }

    const float c = counts[n];
    const float inv = (c > 0.f) ? (1.0f / c) : 0.0f; // counts are integral: max(c,1)==c when c>0
    const float2* ss2 = reinterpret_cast<const float2*>(inout) + (size_t)n * 5;
#pragma unroll
    for (int k = 0; k < 5; ++k) {
        float2 v = ss2[k];
        u[10 + 2 * k] = v.x * inv; u[10 + 2 * k + 1] = v.y * inv;
    }

    float hid[20];
#pragma unroll
    for (int j = 0; j < 20; ++j) hid[j] = lb1[j];
#pragma unroll
    for (int i = 0; i < 20; ++i) {
        float ui = u[i];
#pragma unroll
        for (int j = 0; j < 20; ++j) hid[j] = fmaf(ui, lw1[i][j], hid[j]);
    }
#pragma unroll
    for (int j = 0; j < 20; ++j) hid[j] = fmaxf(hid[j], 0.f);

    float o[10];
#pragma unroll
    for (int k = 0; k < 10; ++k) o[k] = 0.f;
#pragma unroll
    for (int i = 0; i < 20; ++i) {
        float hi = hid[i];
#pragma unroll
        for (int k = 0; k < 10; ++k) o[k] = fmaf(hi, lw2[i][k], o[k]);
    }

    float2* dst = reinterpret_cast<float2*>(inout) + (size_t)n * 5;
#pragma unroll
    for (int k = 0; k < 5; ++k) dst[k] = make_float2(o[2 * k], o[2 * k + 1]);
}

extern "C" void kernel_launch(void* const* d_in, const int* in_sizes, int n_in,
                              void* d_out, int out_size, void* d_ws, size_t ws_size,
                              hipStream_t stream) {
    const float* node_feats    = (const float*)d_in[0];
    const int*   edges         = (const int*)  d_in[1];
    const float* edge_features = (const float*)d_in[2];
    const float* W1p           = (const float*)d_in[3];
    const float* b1p           = (const float*)d_in[4];
    const float* W2p           = (const float*)d_in[5];
    const float* W1u           = (const float*)d_in[6];
    const float* b1u           = (const float*)d_in[7];
    const float* W2u           = (const float*)d_in[8];

    const int N = in_sizes[0] / 10;
    const int E = in_sizes[1] / 2;

    float* seg_sum = (float*)d_out; // [N,10] accumulator, then final output (in-place)
    float* counts  = (float*)d_ws;  // [N] floats — only 4*N bytes of ws used

    {
        int n_out4 = (N * 10) / 4; // N*10 divisible by 4 here
        int n_cnt4 = (N + 3) / 4;
        int mx = n_out4 > n_cnt4 ? n_out4 : n_cnt4;
        zero_kernel<<<(mx + 255) / 256, 256, 0, stream>>>(
            (float4*)seg_sum, n_out4, (float4*)counts, n_cnt4);
    }

    edge_kernel<<<(E + 511) / 512, 256, 0, stream>>>(
        node_feats, edges, edge_features, W1p, b1p, W2p, seg_sum, counts, E);

    node_kernel<<<(N + 255) / 256, 256, 0, stream>>>(
        node_feats, counts, W1u, b1u, W2u, seg_sum, N);
}